// Round 24
// baseline (224.494 us; speedup 1.0000x reference)
//
#include <hip/hip_runtime.h>

constexpr int H  = 16;
constexpr int HD = 48;
constexpr int D  = 768;    // H*HD
constexpr int DZ = 128;
constexpr int S  = 1024;
constexpr float EPS = 1e-5f;

typedef __attribute__((ext_vector_type(8))) short bf16x8;
typedef __attribute__((ext_vector_type(4))) float f32x4;

__device__ __forceinline__ float sigmoidf_(float x) { return 1.f / (1.f + __expf(-x)); }

__device__ __forceinline__ unsigned short f2b(float f) {
  unsigned u = __float_as_uint(f);
  u += 0x7FFFu + ((u >> 16) & 1u);
  return (unsigned short)(u >> 16);
}
__device__ __forceinline__ float b2f(unsigned short u) {
  return __uint_as_float((unsigned)u << 16);
}
__device__ __forceinline__ void split2(float x, unsigned short& h, unsigned short& l) {
  const unsigned short hb = f2b(x);
  const float hf = __uint_as_float((unsigned)hb << 16);
  h = hb;
  l = f2b(x - hf);
}
__device__ __forceinline__ unsigned pack2(unsigned short a, unsigned short b) {
  return (unsigned)a | ((unsigned)b << 16);
}

// ===========================================================================
// prep (unchanged): s + Wq/Wk/Wv/Wg -> bf16 hi only; Wo -> hi+lo.
// pb_prep at block 768,y0; padzero 769+.
// ===========================================================================
__global__ __launch_bounds__(256)
void prep_kernel(const float* __restrict__ s, const float* __restrict__ Wq,
                 const float* __restrict__ Wk, const float* __restrict__ Wv,
                 const float* __restrict__ Wg, const float* __restrict__ Wo,
                 unsigned short* __restrict__ s_hi,
                 unsigned short* __restrict__ w_hi, unsigned short* __restrict__ w_lo,
                 const float* __restrict__ Wz, const float* __restrict__ ln_w,
                 const float* __restrict__ ln_b, unsigned short* __restrict__ wzwb,
                 float* __restrict__ s12,
                 unsigned short* __restrict__ q_hi, unsigned short* __restrict__ k_hi) {
  if (blockIdx.x >= 769) {
    const int pid = (blockIdx.x - 769) * 6 + blockIdx.y;
    if (pid < 256) {
      const int i = pid * 256 + threadIdx.x;     // < 65536
      const int row = i >> 6, rem = i & 63;
      const int h = rem >> 2, off = (rem & 3) << 2;
      const size_t a = (size_t)row * 1024 + h * 64 + 48 + off;
      const ushort4 zz = {0, 0, 0, 0};
      *reinterpret_cast<ushort4*>(q_hi + a) = zz;
      *reinterpret_cast<ushort4*>(k_hi + a) = zz;
    }
    return;
  }
  if (blockIdx.x == 768) {
    if (blockIdx.y != 0) return;
    const int t = threadIdx.x;
    for (int e = t; e < 16 * DZ; e += 256) wzwb[e] = f2b(Wz[e] * ln_w[e & 127]);
    __syncthreads();
    if (t < 32) {
      const int h = t & 15;
      float a = 0.f;
      if (t < 16) {
        for (int c = 0; c < DZ; ++c) {
          const unsigned u = (unsigned)wzwb[h * DZ + c] << 16;
          a += __uint_as_float(u);
        }
      } else {
        for (int c = 0; c < DZ; ++c) a += Wz[h * DZ + c] * ln_b[c];
      }
      s12[t] = a;
    }
    return;
  }
  const int seg = blockIdx.y;
  const float* src;
  unsigned short* dh;
  unsigned short* dl = nullptr;
  int n;
  if (seg == 0) { src = s; dh = s_hi; n = S * D; }
  else {
    src = (seg == 1) ? Wq : (seg == 2) ? Wk : (seg == 3) ? Wv : (seg == 4) ? Wg : Wo;
    dh = w_hi + (size_t)(seg - 1) * D * D;
    if (seg == 5) dl = w_lo;     // only Wo keeps a lo plane
    n = D * D;
  }
  const int i4 = blockIdx.x * 256 + threadIdx.x;
  if (i4 * 4 < n) {
    const float4 v = *reinterpret_cast<const float4*>(src + (size_t)i4 * 4);
    ushort4 hh, ll;
    split2(v.x, hh.x, ll.x); split2(v.y, hh.y, ll.y);
    split2(v.z, hh.z, ll.z); split2(v.w, hh.w, ll.w);
    *reinterpret_cast<ushort4*>(dh + (size_t)i4 * 4) = hh;
    if (dl) *reinterpret_cast<ushort4*>(dl + (size_t)i4 * 4) = ll;
  }
}

// ---------------------------------------------------------------------------
// Plain-bf16 MFMA GEMM core over K range (32x32 tile/wave).
// ---------------------------------------------------------------------------
__device__ __forceinline__ void mfma_core32_bf(const unsigned short* __restrict__ Ah,
                                               const unsigned short* __restrict__ Wh,
                                               const int m0, const int n0,
                                               const int k0, const int k1,
                                               f32x4& a00, f32x4& a01, f32x4& a10, f32x4& a11) {
  const int lane = threadIdx.x & 63;
  const int r16 = lane & 15, kg = lane >> 4;
  const unsigned short* pah = Ah + (size_t)(m0 + r16) * D + kg * 8;
  const unsigned short* pbh = Wh + (size_t)(n0 + r16) * D + kg * 8;
#pragma unroll 2
  for (int k = k0; k < k1; k += 32) {
    const bf16x8 ah0 = *reinterpret_cast<const bf16x8*>(pah + k);
    const bf16x8 ah1 = *reinterpret_cast<const bf16x8*>(pah + 16 * D + k);
    const bf16x8 bh0 = *reinterpret_cast<const bf16x8*>(pbh + k);
    const bf16x8 bh1 = *reinterpret_cast<const bf16x8*>(pbh + 16 * D + k);
    a00 = __builtin_amdgcn_mfma_f32_16x16x32_bf16(ah0, bh0, a00, 0, 0, 0);
    a01 = __builtin_amdgcn_mfma_f32_16x16x32_bf16(ah0, bh1, a01, 0, 0, 0);
    a10 = __builtin_amdgcn_mfma_f32_16x16x32_bf16(ah1, bh0, a10, 0, 0, 0);
    a11 = __builtin_amdgcn_mfma_f32_16x16x32_bf16(ah1, bh1, a11, 0, 0, 0);
  }
}

// ===========================================================================
// qkvg (unchanged): plain-bf16 core; q_hi/k_hi/vt_hi/g. Split-K x2.
// ===========================================================================
__global__ __launch_bounds__(256)
void qkvg_mfma_kernel(const unsigned short* __restrict__ s_hi,
                      const unsigned short* __restrict__ w_hi,
                      const float* __restrict__ bq,
                      unsigned short* __restrict__ q_hi,
                      unsigned short* __restrict__ k_hi,
                      unsigned short* __restrict__ vt_hi,
                      float* __restrict__ g_ws) {
  __shared__ float TT[4][32 * 33];
  __shared__ float CB[2][64][17];
  const int wv = threadIdx.x >> 6;
  const int pair = wv >> 1;
  const int khalf = wv & 1;
  const int tileid = blockIdx.x * 2 + pair;   // 0..3071
  const int wsel = tileid / 768;
  const int rr = tileid % 768;
  const int m0 = (rr / 24) * 32, n0 = (rr % 24) * 32;
  f32x4 a00 = {0.f, 0.f, 0.f, 0.f}, a01 = a00, a10 = a00, a11 = a00;
  mfma_core32_bf(s_hi, w_hi + (size_t)wsel * D * D,
                 m0, n0, khalf * 384, khalf * 384 + 384, a00, a01, a10, a11);
  const int lane = threadIdx.x & 63;
  const int r16 = lane & 15, kg = lane >> 4;
  const float scale = 0.14433756729740643f;  // 1/sqrt(48)

  if (khalf == 1) {
#pragma unroll
    for (int r = 0; r < 4; ++r) {
      CB[pair][lane][r] = a00[r];
      CB[pair][lane][4 + r] = a01[r];
      CB[pair][lane][8 + r] = a10[r];
      CB[pair][lane][12 + r] = a11[r];
    }
  }
  __syncthreads();
  if (khalf == 1) return;
#pragma unroll
  for (int r = 0; r < 4; ++r) {
    a00[r] += CB[pair][lane][r];
    a01[r] += CB[pair][lane][4 + r];
    a10[r] += CB[pair][lane][8 + r];
    a11[r] += CB[pair][lane][12 + r];
  }

  float* T = TT[wv];
#pragma unroll
  for (int r = 0; r < 4; ++r) {
    T[(kg * 4 + r) * 33 + r16] = a00[r];
    T[(kg * 4 + r) * 33 + 16 + r16] = a01[r];
    T[(16 + kg * 4 + r) * 33 + r16] = a10[r];
    T[(16 + kg * 4 + r) * 33 + 16 + r16] = a11[r];
  }
  const int rr2 = lane >> 1, run = lane & 1;
  if (wsel <= 1) {
    const int row = m0 + rr2;
    const int col0 = n0 + run * 16;
    const int hcol0 = (col0 / 48) * 64 + (col0 % 48);
    unsigned short* dh = (wsel == 0) ? q_hi : k_hi;
#pragma unroll
    for (int p4 = 0; p4 < 4; ++p4) {
      float v0 = T[rr2 * 33 + run * 16 + p4 * 4 + 0];
      float v1 = T[rr2 * 33 + run * 16 + p4 * 4 + 1];
      float v2 = T[rr2 * 33 + run * 16 + p4 * 4 + 2];
      float v3 = T[rr2 * 33 + run * 16 + p4 * 4 + 3];
      if (wsel == 0) {
        v0 = (v0 + bq[col0 + p4 * 4 + 0]) * scale;
        v1 = (v1 + bq[col0 + p4 * 4 + 1]) * scale;
        v2 = (v2 + bq[col0 + p4 * 4 + 2]) * scale;
        v3 = (v3 + bq[col0 + p4 * 4 + 3]) * scale;
      }
      uint2 uh;
      uh.x = pack2(f2b(v0), f2b(v1)); uh.y = pack2(f2b(v2), f2b(v3));
      *reinterpret_cast<uint2*>(dh + (size_t)row * 1024 + hcol0 + p4 * 4) = uh;
    }
  } else if (wsel == 2) {
    const int c = lane >> 1;
    const int run2 = lane & 1;
    const int vc = n0 + c;
#pragma unroll
    for (int p4 = 0; p4 < 4; ++p4) {
      uint2 uh;
      uh.x = pack2(f2b(T[(run2 * 16 + p4 * 4 + 0) * 33 + c]),
                   f2b(T[(run2 * 16 + p4 * 4 + 1) * 33 + c]));
      uh.y = pack2(f2b(T[(run2 * 16 + p4 * 4 + 2) * 33 + c]),
                   f2b(T[(run2 * 16 + p4 * 4 + 3) * 33 + c]));
      *reinterpret_cast<uint2*>(vt_hi + (size_t)vc * 1024 + m0 + run2 * 16 + p4 * 4) = uh;
    }
  } else {
    const int row = m0 + rr2;
#pragma unroll
    for (int p4 = 0; p4 < 4; ++p4) {
      float4 v4;
      v4.x = T[rr2 * 33 + run * 16 + p4 * 4 + 0];
      v4.y = T[rr2 * 33 + run * 16 + p4 * 4 + 1];
      v4.z = T[rr2 * 33 + run * 16 + p4 * 4 + 2];
      v4.w = T[rr2 * 33 + run * 16 + p4 * 4 + 3];
      *reinterpret_cast<float4*>(g_ws + (size_t)row * D + n0 + run * 16 + p4 * 4) = v4;
    }
  }
}

// ---------------------------------------------------------------------------
// pair_bias (unchanged): MFMA z@WzW^T, LN folded, bf16 bias out.
// ---------------------------------------------------------------------------
__global__ __launch_bounds__(256)
void pair_bias_kernel(const float* __restrict__ z, const unsigned short* __restrict__ wzwb,
                      const float* __restrict__ s12, unsigned short* __restrict__ bias_out) {
  __shared__ float T[4][64 * 17];
  const int tid = threadIdx.x;
  const int lane = tid & 63;
  const int wv = tid >> 6;
  const int hq = lane & 15;
  const int grp = lane >> 4;

  bf16x8 bf[4];
#pragma unroll
  for (int m = 0; m < 4; ++m)
    bf[m] = *reinterpret_cast<const bf16x8*>(wzwb + hq * DZ + m * 32 + grp * 8);
  const float S1h = s12[hq], S2h = s12[16 + hq];

  const int chunk = blockIdx.x * 4 + wv;
  const size_t p0 = (size_t)chunk * 64;
  float* Tw = &T[wv][0];

#pragma unroll 1
  for (int sub = 0; sub < 4; ++sub) {
    const float* zr = z + (p0 + sub * 16 + hq) * DZ + grp * 8;
    f32x4 acc = {0.f, 0.f, 0.f, 0.f};
    float s1 = 0.f, s2 = 0.f;
#pragma unroll
    for (int m = 0; m < 4; ++m) {
      const float4 a0 = *reinterpret_cast<const float4*>(zr + m * 32);
      const float4 a1 = *reinterpret_cast<const float4*>(zr + m * 32 + 4);
      s1 += (a0.x + a0.y) + (a0.z + a0.w) + (a1.x + a1.y) + (a1.z + a1.w);
      s2 = fmaf(a0.x, a0.x, fmaf(a0.y, a0.y, fmaf(a0.z, a0.z, fmaf(a0.w, a0.w, s2))));
      s2 = fmaf(a1.x, a1.x, fmaf(a1.y, a1.y, fmaf(a1.z, a1.z, fmaf(a1.w, a1.w, s2))));
      bf16x8 af;
      af[0] = (short)f2b(a0.x); af[1] = (short)f2b(a0.y);
      af[2] = (short)f2b(a0.z); af[3] = (short)f2b(a0.w);
      af[4] = (short)f2b(a1.x); af[5] = (short)f2b(a1.y);
      af[6] = (short)f2b(a1.z); af[7] = (short)f2b(a1.w);
      acc = __builtin_amdgcn_mfma_f32_16x16x32_bf16(af, bf[m], acc, 0, 0, 0);
    }
    s1 += __shfl_xor(s1, 16); s1 += __shfl_xor(s1, 32);
    s2 += __shfl_xor(s2, 16); s2 += __shfl_xor(s2, 32);
    const float mu = s1 * (1.f / DZ);
    const float inv = rsqrtf(s2 * (1.f / DZ) - mu * mu + EPS);
#pragma unroll
    for (int r = 0; r < 4; ++r) {
      const int st = grp * 4 + r;
      const float mur = __shfl(mu, st);
      const float invr = __shfl(inv, st);
      Tw[(sub * 16 + st) * 17 + hq] = invr * (acc[r] - mur * S1h) + S2h;
    }
  }
#pragma unroll
  for (int hh = 0; hh < 16; ++hh)
    bias_out[(size_t)hh * S * S + p0 + lane] = f2b(Tw[lane * 17 + hh]);
}

// ===========================================================================
// Attention v8: 8-way intra-block KV-split. Block = (h, 16 q-rows), 512
// threads = 8 waves; wave wv owns keys [wv*128, wv*128+128) (2 t0-iters,
// half the round-23 serial chain). LDS 44KB -> 3 blocks/CU = 24 waves/CU
// (6/SIMD, was 4/SIMD). Combine generalizes 4->8 partials; epilogue on
// threads 0..255. QK hi-only, bias bf16, PV hi-only, gate fused (as r23).
// ===========================================================================
constexpr int PST = 72;   // P slab stride (u16)
constexpr int PRS = 50;   // partial-result row stride (f32): 48 O + m + l

__global__ __launch_bounds__(512)
void attn_kernel(const unsigned short* __restrict__ q_hi,
                 const unsigned short* __restrict__ k_hi,
                 const unsigned short* __restrict__ vt_hi,
                 const unsigned short* __restrict__ bias, const float* __restrict__ g,
                 unsigned short* __restrict__ a_hi) {
  __shared__ unsigned short Ph[8][16 * PST];   // 18.4 KB
  __shared__ float Pr[8][16 * PRS];            // 25.6 KB
  const int lane = threadIdx.x & 63;
  const int wv = threadIdx.x >> 6;             // 0..7 (KV partition)
  const int h = blockIdx.x >> 6;
  const int qb = blockIdx.x & 63;
  const int q0 = qb << 4;
  const int n16 = lane & 15, kg = lane >> 4;

  const size_t qbase = (size_t)(q0 + n16) * 1024 + h * 64;
  const bf16x8 qh0 = *reinterpret_cast<const bf16x8*>(q_hi + qbase + kg * 8);
  const bf16x8 qh1 = *reinterpret_cast<const bf16x8*>(q_hi + qbase + 32 + kg * 8);

  float mrow = -1e30f, lrow = 0.f;
  f32x4 accO[3] = {};
  unsigned short* php = Ph[wv];

#pragma unroll 1
  for (int t0 = wv * 128; t0 < wv * 128 + 128; t0 += 64) {
    f32x4 sc[4];
#pragma unroll
    for (int ts = 0; ts < 4; ++ts) {
      const size_t kb = (size_t)(t0 + ts * 16 + n16) * 1024 + h * 64;
      const bf16x8 kh0 = *reinterpret_cast<const bf16x8*>(k_hi + kb + kg * 8);
      const bf16x8 kh1 = *reinterpret_cast<const bf16x8*>(k_hi + kb + 32 + kg * 8);
      const ushort4 b4 = *reinterpret_cast<const ushort4*>(
          bias + (size_t)h * S * S + (size_t)(q0 + n16) * S + t0 + ts * 16 + kg * 4);
      f32x4 a;
      a[0] = b2f(b4.x); a[1] = b2f(b4.y); a[2] = b2f(b4.z); a[3] = b2f(b4.w);
      a = __builtin_amdgcn_mfma_f32_16x16x32_bf16(kh0, qh0, a, 0, 0, 0);
      a = __builtin_amdgcn_mfma_f32_16x16x32_bf16(kh1, qh1, a, 0, 0, 0);
      sc[ts] = a;
    }

    float tmax = sc[0][0];
#pragma unroll
    for (int ts = 0; ts < 4; ++ts)
#pragma unroll
      for (int r = 0; r < 4; ++r) tmax = fmaxf(tmax, sc[ts][r]);
    tmax = fmaxf(tmax, __shfl_xor(tmax, 16));
    tmax = fmaxf(tmax, __shfl_xor(tmax, 32));
    const float mn = fmaxf(mrow, tmax);
    const float fac = __expf(mrow - mn);
    mrow = mn;
    float psum = 0.f;
#pragma unroll
    for (int ts = 0; ts < 4; ++ts) {
      const float p0_ = __expf(sc[ts][0] - mn), p1_ = __expf(sc[ts][1] - mn);
      const float p2_ = __expf(sc[ts][2] - mn), p3_ = __expf(sc[ts][3] - mn);
      psum += (p0_ + p1_) + (p2_ + p3_);
      const int ti = ts * 16 + kg * 4;
      unsigned* wh = reinterpret_cast<unsigned*>(&php[n16 * PST + ti]);
      wh[0] = pack2(f2b(p0_), f2b(p1_));
      wh[1] = pack2(f2b(p2_), f2b(p3_));
    }
    lrow = lrow * fac + psum;

    float facr[4];
#pragma unroll
    for (int r = 0; r < 4; ++r) facr[r] = __shfl(fac, kg * 4 + r);
#pragma unroll
    for (int ds = 0; ds < 3; ++ds)
#pragma unroll
      for (int r = 0; r < 4; ++r) accO[ds][r] *= facr[r];

#pragma unroll
    for (int c = 0; c < 2; ++c) {
      const bf16x8 pah = *reinterpret_cast<const bf16x8*>(&php[n16 * PST + c * 32 + kg * 8]);
#pragma unroll
      for (int ds = 0; ds < 3; ++ds) {
        const size_t vb = (size_t)(h * 48 + ds * 16 + n16) * 1024 + t0 + c * 32 + kg * 8;
        const bf16x8 vh = *reinterpret_cast<const bf16x8*>(vt_hi + vb);
        accO[ds] = __builtin_amdgcn_mfma_f32_16x16x32_bf16(pah, vh, accO[ds], 0, 0, 0);
      }
    }
  }

  lrow += __shfl_xor(lrow, 16);
  lrow += __shfl_xor(lrow, 32);

  // deposit partials
  float* pw = Pr[wv];
#pragma unroll
  for (int ds = 0; ds < 3; ++ds)
#pragma unroll
    for (int r = 0; r < 4; ++r)
      pw[(kg * 4 + r) * PRS + ds * 16 + n16] = accO[ds][r];
  if (kg == 0) {
    pw[n16 * PRS + 48] = mrow;
    pw[n16 * PRS + 49] = lrow;
  }
  __syncthreads();

  // combine 8 partials + gate + store (threads 0..255)
  if (threadIdx.x < 256) {
    const int row = threadIdx.x >> 4;
    const int dsub = threadIdx.x & 15;
    float mp[8], lp[8];
#pragma unroll
    for (int p = 0; p < 8; ++p) {
      mp[p] = Pr[p][row * PRS + 48];
      lp[p] = Pr[p][row * PRS + 49];
    }
    float M = mp[0];
#pragma unroll
    for (int p = 1; p < 8; ++p) M = fmaxf(M, mp[p]);
    float ep[8];
    float denom = 0.f;
#pragma unroll
    for (int p = 0; p < 8; ++p) {
      ep[p] = __expf(mp[p] - M);
      denom += lp[p] * ep[p];
    }
    const float rl = 1.f / denom;
#pragma unroll
    for (int j = 0; j < 3; ++j) {
      const int d = dsub * 3 + j;
      float o = 0.f;
#pragma unroll
      for (int p = 0; p < 8; ++p) o += Pr[p][row * PRS + d] * ep[p];
      o *= rl;
      const size_t idx = (size_t)(q0 + row) * D + h * 48 + d;
      const float a = o * sigmoidf_(g[idx]);
      a_hi[idx] = f2b(a);
    }
  }
}

// ===========================================================================
// outproj (unchanged): a_hi x (Wo_hi + Wo_lo), split-K x2.
// ===========================================================================
__global__ __launch_bounds__(256)
void outproj_mfma_kernel(const unsigned short* __restrict__ a_hi,
                         const unsigned short* __restrict__ wo_hi,
                         const unsigned short* __restrict__ wo_lo,
                         float* __restrict__ out) {
  __shared__ float CB[2][64][9];
  const int wv = threadIdx.x >> 6;
  const int pair = wv >> 1;
  const int khalf = wv & 1;
  const int tileid = blockIdx.x * 2 + pair;   // 0..1535
  const int m0 = (tileid / 48) * 32, n0 = (tileid % 48) * 16;
  const int lane = threadIdx.x & 63;
  const int r16 = lane & 15, kg = lane >> 4;
  const unsigned short* pah = a_hi + (size_t)(m0 + r16) * D + kg * 8;
  const unsigned short* pbh = wo_hi + (size_t)(n0 + r16) * D + kg * 8;
  const unsigned short* pbl = wo_lo + (size_t)(n0 + r16) * D + kg * 8;
  f32x4 a0 = {0.f, 0.f, 0.f, 0.f}, a1 = a0;
#pragma unroll 2
  for (int k = khalf * 384; k < khalf * 384 + 384; k += 32) {
    const bf16x8 ah0 = *reinterpret_cast<const bf16x8*>(pah + k);
    const bf16x8 ah1 = *reinterpret_cast<const bf16x8*>(pah + 16 * D + k);
    const bf16x8 bh0 = *reinterpret_cast<const bf16x8*>(pbh + k);
    const bf16x8 bl0 = *reinterpret_cast<const bf16x8*>(pbl + k);
    a0 = __builtin_amdgcn_mfma_f32_16x16x32_bf16(ah0, bh0, a0, 0, 0, 0);
    a0 = __builtin_amdgcn_mfma_f32_16x16x32_bf16(ah0, bl0, a0, 0, 0, 0);
    a1 = __builtin_amdgcn_mfma_f32_16x16x32_bf16(ah1, bh0, a1, 0, 0, 0);
    a1 = __builtin_amdgcn_mfma_f32_16x16x32_bf16(ah1, bl0, a1, 0, 0, 0);
  }
  if (khalf == 1) {
#pragma unroll
    for (int r = 0; r < 4; ++r) {
      CB[pair][lane][r] = a0[r];
      CB[pair][lane][4 + r] = a1[r];
    }
  }
  __syncthreads();
  if (khalf == 1) return;
#pragma unroll
  for (int r = 0; r < 4; ++r) {
    a0[r] += CB[pair][lane][r];
    a1[r] += CB[pair][lane][4 + r];
  }
#pragma unroll
  for (int r = 0; r < 4; ++r) {
    out[(size_t)(m0 + kg * 4 + r) * D + n0 + r16] = a0[r];
    out[(size_t)(m0 + 16 + kg * 4 + r) * D + n0 + r16] = a1[r];
  }
}

extern "C" void kernel_launch(void* const* d_in, const int* in_sizes, int n_in,
                              void* d_out, int out_size, void* d_ws, size_t ws_size,
                              hipStream_t stream) {
  const float* s    = (const float*)d_in[0];
  const float* z    = (const float*)d_in[1];
  const float* Wq   = (const float*)d_in[2];
  const float* bq   = (const float*)d_in[3];
  const float* Wk   = (const float*)d_in[4];
  const float* Wv   = (const float*)d_in[5];
  const float* Wg   = (const float*)d_in[6];
  const float* ln_w = (const float*)d_in[7];
  const float* ln_b = (const float*)d_in[8];
  const float* Wz   = (const float*)d_in[9];
  const float* Wo   = (const float*)d_in[10];
  float* out = (float*)d_out;

  float* g_ws    = (float*)d_ws;                                  // S*D f32
  float* s12_ws  = g_ws + (size_t)S * D;                          // 32 f32
  unsigned short* bias16 = (unsigned short*)(s12_ws + 32);        // H*S*S u16 (bf16)
  unsigned short* wzwb_ws = bias16 + (size_t)H * S * S;           // 2048 u16
  unsigned short* s_hi = wzwb_ws + 2048;                          // S*D
  unsigned short* w_hi = s_hi + (size_t)S * D;                    // 5*D*D
  unsigned short* wo_lo = w_hi + (size_t)5 * D * D;               // D*D (Wo lo)
  unsigned short* a_hi = wo_lo + (size_t)D * D;                   // S*D
  unsigned short* q_hi = a_hi + (size_t)S * D;                    // [S][1024] padded
  unsigned short* k_hi = q_hi + (size_t)S * 1024;
  unsigned short* vt_hi = k_hi + (size_t)S * 1024;                // [768][1024]

  // A) splits (hi-only except Wo) + pb_prep + padzero
  prep_kernel<<<dim3(812, 6), 256, 0, stream>>>(s, Wq, Wk, Wv, Wg, Wo,
                                                s_hi, w_hi, wo_lo,
                                                Wz, ln_w, ln_b, wzwb_ws, s12_ws,
                                                q_hi, k_hi);
  // B) qkvg (plain bf16, split-K x2) + pair_bias (bf16 bias out)
  qkvg_mfma_kernel<<<1536, 256, 0, stream>>>(s_hi, w_hi, bq,
                                             q_hi, k_hi, vt_hi, g_ws);
  pair_bias_kernel<<<4096, 256, 0, stream>>>(z, wzwb_ws, s12_ws, bias16);
  // C) fused 8-way KV-split attention (QK hi; bias bf16; PV hi; gate fused)
  attn_kernel<<<1024, 512, 0, stream>>>(q_hi, k_hi, vt_hi,
                                        bias16, g_ws, a_hi);
  // D) output projection (a hi x Wo split)
  outproj_mfma_kernel<<<768, 256, 0, stream>>>(a_hi, w_hi + (size_t)4 * D * D,
                                               wo_lo, out);
}

// Round 25
// 222.157 us; speedup vs baseline: 1.0105x; 1.0105x over previous
//
#include <hip/hip_runtime.h>

constexpr int H  = 16;
constexpr int HD = 48;
constexpr int D  = 768;    // H*HD
constexpr int DZ = 128;
constexpr int S  = 1024;
constexpr float EPS = 1e-5f;

typedef __attribute__((ext_vector_type(8))) short bf16x8;
typedef __attribute__((ext_vector_type(4))) float f32x4;

__device__ __forceinline__ float sigmoidf_(float x) { return 1.f / (1.f + __expf(-x)); }

__device__ __forceinline__ unsigned short f2b(float f) {
  unsigned u = __float_as_uint(f);
  u += 0x7FFFu + ((u >> 16) & 1u);
  return (unsigned short)(u >> 16);
}
__device__ __forceinline__ float b2f(unsigned short u) {
  return __uint_as_float((unsigned)u << 16);
}
__device__ __forceinline__ void split2(float x, unsigned short& h, unsigned short& l) {
  const unsigned short hb = f2b(x);
  const float hf = __uint_as_float((unsigned)hb << 16);
  h = hb;
  l = f2b(x - hf);
}
__device__ __forceinline__ unsigned pack2(unsigned short a, unsigned short b) {
  return (unsigned)a | ((unsigned)b << 16);
}

// ===========================================================================
// prep: s + Wq/Wk/Wv/Wg -> bf16 hi only; Wo -> hi+lo.
// pb_prep at block 768,y0; padzero 769+.
// ===========================================================================
__global__ __launch_bounds__(256)
void prep_kernel(const float* __restrict__ s, const float* __restrict__ Wq,
                 const float* __restrict__ Wk, const float* __restrict__ Wv,
                 const float* __restrict__ Wg, const float* __restrict__ Wo,
                 unsigned short* __restrict__ s_hi,
                 unsigned short* __restrict__ w_hi, unsigned short* __restrict__ w_lo,
                 const float* __restrict__ Wz, const float* __restrict__ ln_w,
                 const float* __restrict__ ln_b, unsigned short* __restrict__ wzwb,
                 float* __restrict__ s12,
                 unsigned short* __restrict__ q_hi, unsigned short* __restrict__ k_hi) {
  if (blockIdx.x >= 769) {
    const int pid = (blockIdx.x - 769) * 6 + blockIdx.y;
    if (pid < 256) {
      const int i = pid * 256 + threadIdx.x;     // < 65536
      const int row = i >> 6, rem = i & 63;
      const int h = rem >> 2, off = (rem & 3) << 2;
      const size_t a = (size_t)row * 1024 + h * 64 + 48 + off;
      const ushort4 zz = {0, 0, 0, 0};
      *reinterpret_cast<ushort4*>(q_hi + a) = zz;
      *reinterpret_cast<ushort4*>(k_hi + a) = zz;
    }
    return;
  }
  if (blockIdx.x == 768) {
    if (blockIdx.y != 0) return;
    const int t = threadIdx.x;
    for (int e = t; e < 16 * DZ; e += 256) wzwb[e] = f2b(Wz[e] * ln_w[e & 127]);
    __syncthreads();
    if (t < 32) {
      const int h = t & 15;
      float a = 0.f;
      if (t < 16) {
        for (int c = 0; c < DZ; ++c) {
          const unsigned u = (unsigned)wzwb[h * DZ + c] << 16;
          a += __uint_as_float(u);
        }
      } else {
        for (int c = 0; c < DZ; ++c) a += Wz[h * DZ + c] * ln_b[c];
      }
      s12[t] = a;
    }
    return;
  }
  const int seg = blockIdx.y;
  const float* src;
  unsigned short* dh;
  unsigned short* dl = nullptr;
  int n;
  if (seg == 0) { src = s; dh = s_hi; n = S * D; }
  else {
    src = (seg == 1) ? Wq : (seg == 2) ? Wk : (seg == 3) ? Wv : (seg == 4) ? Wg : Wo;
    dh = w_hi + (size_t)(seg - 1) * D * D;
    if (seg == 5) dl = w_lo;     // only Wo keeps a lo plane
    n = D * D;
  }
  const int i4 = blockIdx.x * 256 + threadIdx.x;
  if (i4 * 4 < n) {
    const float4 v = *reinterpret_cast<const float4*>(src + (size_t)i4 * 4);
    ushort4 hh, ll;
    split2(v.x, hh.x, ll.x); split2(v.y, hh.y, ll.y);
    split2(v.z, hh.z, ll.z); split2(v.w, hh.w, ll.w);
    *reinterpret_cast<ushort4*>(dh + (size_t)i4 * 4) = hh;
    if (dl) *reinterpret_cast<ushort4*>(dl + (size_t)i4 * 4) = ll;
  }
}

// ---------------------------------------------------------------------------
// Plain-bf16 MFMA GEMM core over K range (32x32 tile/wave).
// ---------------------------------------------------------------------------
__device__ __forceinline__ void mfma_core32_bf(const unsigned short* __restrict__ Ah,
                                               const unsigned short* __restrict__ Wh,
                                               const int m0, const int n0,
                                               const int k0, const int k1,
                                               f32x4& a00, f32x4& a01, f32x4& a10, f32x4& a11) {
  const int lane = threadIdx.x & 63;
  const int r16 = lane & 15, kg = lane >> 4;
  const unsigned short* pah = Ah + (size_t)(m0 + r16) * D + kg * 8;
  const unsigned short* pbh = Wh + (size_t)(n0 + r16) * D + kg * 8;
#pragma unroll 2
  for (int k = k0; k < k1; k += 32) {
    const bf16x8 ah0 = *reinterpret_cast<const bf16x8*>(pah + k);
    const bf16x8 ah1 = *reinterpret_cast<const bf16x8*>(pah + 16 * D + k);
    const bf16x8 bh0 = *reinterpret_cast<const bf16x8*>(pbh + k);
    const bf16x8 bh1 = *reinterpret_cast<const bf16x8*>(pbh + 16 * D + k);
    a00 = __builtin_amdgcn_mfma_f32_16x16x32_bf16(ah0, bh0, a00, 0, 0, 0);
    a01 = __builtin_amdgcn_mfma_f32_16x16x32_bf16(ah0, bh1, a01, 0, 0, 0);
    a10 = __builtin_amdgcn_mfma_f32_16x16x32_bf16(ah1, bh0, a10, 0, 0, 0);
    a11 = __builtin_amdgcn_mfma_f32_16x16x32_bf16(ah1, bh1, a11, 0, 0, 0);
  }
}

// ===========================================================================
// qkvg: plain-bf16 core; q_hi/k_hi/vt_hi/g. Split-K x2.
// ===========================================================================
__global__ __launch_bounds__(256)
void qkvg_mfma_kernel(const unsigned short* __restrict__ s_hi,
                      const unsigned short* __restrict__ w_hi,
                      const float* __restrict__ bq,
                      unsigned short* __restrict__ q_hi,
                      unsigned short* __restrict__ k_hi,
                      unsigned short* __restrict__ vt_hi,
                      float* __restrict__ g_ws) {
  __shared__ float TT[4][32 * 33];
  __shared__ float CB[2][64][17];
  const int wv = threadIdx.x >> 6;
  const int pair = wv >> 1;
  const int khalf = wv & 1;
  const int tileid = blockIdx.x * 2 + pair;   // 0..3071
  const int wsel = tileid / 768;
  const int rr = tileid % 768;
  const int m0 = (rr / 24) * 32, n0 = (rr % 24) * 32;
  f32x4 a00 = {0.f, 0.f, 0.f, 0.f}, a01 = a00, a10 = a00, a11 = a00;
  mfma_core32_bf(s_hi, w_hi + (size_t)wsel * D * D,
                 m0, n0, khalf * 384, khalf * 384 + 384, a00, a01, a10, a11);
  const int lane = threadIdx.x & 63;
  const int r16 = lane & 15, kg = lane >> 4;
  const float scale = 0.14433756729740643f;  // 1/sqrt(48)

  if (khalf == 1) {
#pragma unroll
    for (int r = 0; r < 4; ++r) {
      CB[pair][lane][r] = a00[r];
      CB[pair][lane][4 + r] = a01[r];
      CB[pair][lane][8 + r] = a10[r];
      CB[pair][lane][12 + r] = a11[r];
    }
  }
  __syncthreads();
  if (khalf == 1) return;
#pragma unroll
  for (int r = 0; r < 4; ++r) {
    a00[r] += CB[pair][lane][r];
    a01[r] += CB[pair][lane][4 + r];
    a10[r] += CB[pair][lane][8 + r];
    a11[r] += CB[pair][lane][12 + r];
  }

  float* T = TT[wv];
#pragma unroll
  for (int r = 0; r < 4; ++r) {
    T[(kg * 4 + r) * 33 + r16] = a00[r];
    T[(kg * 4 + r) * 33 + 16 + r16] = a01[r];
    T[(16 + kg * 4 + r) * 33 + r16] = a10[r];
    T[(16 + kg * 4 + r) * 33 + 16 + r16] = a11[r];
  }
  const int rr2 = lane >> 1, run = lane & 1;
  if (wsel <= 1) {
    const int row = m0 + rr2;
    const int col0 = n0 + run * 16;
    const int hcol0 = (col0 / 48) * 64 + (col0 % 48);
    unsigned short* dh = (wsel == 0) ? q_hi : k_hi;
#pragma unroll
    for (int p4 = 0; p4 < 4; ++p4) {
      float v0 = T[rr2 * 33 + run * 16 + p4 * 4 + 0];
      float v1 = T[rr2 * 33 + run * 16 + p4 * 4 + 1];
      float v2 = T[rr2 * 33 + run * 16 + p4 * 4 + 2];
      float v3 = T[rr2 * 33 + run * 16 + p4 * 4 + 3];
      if (wsel == 0) {
        v0 = (v0 + bq[col0 + p4 * 4 + 0]) * scale;
        v1 = (v1 + bq[col0 + p4 * 4 + 1]) * scale;
        v2 = (v2 + bq[col0 + p4 * 4 + 2]) * scale;
        v3 = (v3 + bq[col0 + p4 * 4 + 3]) * scale;
      }
      uint2 uh;
      uh.x = pack2(f2b(v0), f2b(v1)); uh.y = pack2(f2b(v2), f2b(v3));
      *reinterpret_cast<uint2*>(dh + (size_t)row * 1024 + hcol0 + p4 * 4) = uh;
    }
  } else if (wsel == 2) {
    const int c = lane >> 1;
    const int run2 = lane & 1;
    const int vc = n0 + c;
#pragma unroll
    for (int p4 = 0; p4 < 4; ++p4) {
      uint2 uh;
      uh.x = pack2(f2b(T[(run2 * 16 + p4 * 4 + 0) * 33 + c]),
                   f2b(T[(run2 * 16 + p4 * 4 + 1) * 33 + c]));
      uh.y = pack2(f2b(T[(run2 * 16 + p4 * 4 + 2) * 33 + c]),
                   f2b(T[(run2 * 16 + p4 * 4 + 3) * 33 + c]));
      *reinterpret_cast<uint2*>(vt_hi + (size_t)vc * 1024 + m0 + run2 * 16 + p4 * 4) = uh;
    }
  } else {
    const int row = m0 + rr2;
#pragma unroll
    for (int p4 = 0; p4 < 4; ++p4) {
      float4 v4;
      v4.x = T[rr2 * 33 + run * 16 + p4 * 4 + 0];
      v4.y = T[rr2 * 33 + run * 16 + p4 * 4 + 1];
      v4.z = T[rr2 * 33 + run * 16 + p4 * 4 + 2];
      v4.w = T[rr2 * 33 + run * 16 + p4 * 4 + 3];
      *reinterpret_cast<float4*>(g_ws + (size_t)row * D + n0 + run * 16 + p4 * 4) = v4;
    }
  }
}

// ---------------------------------------------------------------------------
// pair_bias: MFMA z@WzW^T, LN folded, bf16 bias out.
// ---------------------------------------------------------------------------
__global__ __launch_bounds__(256)
void pair_bias_kernel(const float* __restrict__ z, const unsigned short* __restrict__ wzwb,
                      const float* __restrict__ s12, unsigned short* __restrict__ bias_out) {
  __shared__ float T[4][64 * 17];
  const int tid = threadIdx.x;
  const int lane = tid & 63;
  const int wv = tid >> 6;
  const int hq = lane & 15;
  const int grp = lane >> 4;

  bf16x8 bf[4];
#pragma unroll
  for (int m = 0; m < 4; ++m)
    bf[m] = *reinterpret_cast<const bf16x8*>(wzwb + hq * DZ + m * 32 + grp * 8);
  const float S1h = s12[hq], S2h = s12[16 + hq];

  const int chunk = blockIdx.x * 4 + wv;
  const size_t p0 = (size_t)chunk * 64;
  float* Tw = &T[wv][0];

#pragma unroll 1
  for (int sub = 0; sub < 4; ++sub) {
    const float* zr = z + (p0 + sub * 16 + hq) * DZ + grp * 8;
    f32x4 acc = {0.f, 0.f, 0.f, 0.f};
    float s1 = 0.f, s2 = 0.f;
#pragma unroll
    for (int m = 0; m < 4; ++m) {
      const float4 a0 = *reinterpret_cast<const float4*>(zr + m * 32);
      const float4 a1 = *reinterpret_cast<const float4*>(zr + m * 32 + 4);
      s1 += (a0.x + a0.y) + (a0.z + a0.w) + (a1.x + a1.y) + (a1.z + a1.w);
      s2 = fmaf(a0.x, a0.x, fmaf(a0.y, a0.y, fmaf(a0.z, a0.z, fmaf(a0.w, a0.w, s2))));
      s2 = fmaf(a1.x, a1.x, fmaf(a1.y, a1.y, fmaf(a1.z, a1.z, fmaf(a1.w, a1.w, s2))));
      bf16x8 af;
      af[0] = (short)f2b(a0.x); af[1] = (short)f2b(a0.y);
      af[2] = (short)f2b(a0.z); af[3] = (short)f2b(a0.w);
      af[4] = (short)f2b(a1.x); af[5] = (short)f2b(a1.y);
      af[6] = (short)f2b(a1.z); af[7] = (short)f2b(a1.w);
      acc = __builtin_amdgcn_mfma_f32_16x16x32_bf16(af, bf[m], acc, 0, 0, 0);
    }
    s1 += __shfl_xor(s1, 16); s1 += __shfl_xor(s1, 32);
    s2 += __shfl_xor(s2, 16); s2 += __shfl_xor(s2, 32);
    const float mu = s1 * (1.f / DZ);
    const float inv = rsqrtf(s2 * (1.f / DZ) - mu * mu + EPS);
#pragma unroll
    for (int r = 0; r < 4; ++r) {
      const int st = grp * 4 + r;
      const float mur = __shfl(mu, st);
      const float invr = __shfl(inv, st);
      Tw[(sub * 16 + st) * 17 + hq] = invr * (acc[r] - mur * S1h) + S2h;
    }
  }
#pragma unroll
  for (int hh = 0; hh < 16; ++hh)
    bias_out[(size_t)hh * S * S + p0 + lane] = f2b(Tw[lane * 17 + hh]);
}

// ===========================================================================
// Attention (round-23 proven config): 4-way intra-block KV-split, fused
// reduce. QK^T hi-only; bias bf16 into MFMA C; PV = P_hi x V_hi; gate fused.
// ===========================================================================
constexpr int PST = 72;   // P slab stride (u16)
constexpr int PRS = 52;   // partial-result row stride (f32)

__global__ __launch_bounds__(256)
void attn_kernel(const unsigned short* __restrict__ q_hi,
                 const unsigned short* __restrict__ k_hi,
                 const unsigned short* __restrict__ vt_hi,
                 const unsigned short* __restrict__ bias, const float* __restrict__ g,
                 unsigned short* __restrict__ a_hi) {
  __shared__ unsigned short Ph[4][16 * PST];
  __shared__ float Pr[4][16 * PRS];
  const int lane = threadIdx.x & 63;
  const int wv = threadIdx.x >> 6;
  const int h = blockIdx.x >> 6;
  const int qb = blockIdx.x & 63;
  const int q0 = qb << 4;
  const int n16 = lane & 15, kg = lane >> 4;

  const size_t qbase = (size_t)(q0 + n16) * 1024 + h * 64;
  const bf16x8 qh0 = *reinterpret_cast<const bf16x8*>(q_hi + qbase + kg * 8);
  const bf16x8 qh1 = *reinterpret_cast<const bf16x8*>(q_hi + qbase + 32 + kg * 8);

  float mrow = -1e30f, lrow = 0.f;
  f32x4 accO[3] = {};
  unsigned short* php = Ph[wv];

#pragma unroll 1
  for (int t0 = wv * 256; t0 < wv * 256 + 256; t0 += 64) {
    f32x4 sc[4];
#pragma unroll
    for (int ts = 0; ts < 4; ++ts) {
      const size_t kb = (size_t)(t0 + ts * 16 + n16) * 1024 + h * 64;
      const bf16x8 kh0 = *reinterpret_cast<const bf16x8*>(k_hi + kb + kg * 8);
      const bf16x8 kh1 = *reinterpret_cast<const bf16x8*>(k_hi + kb + 32 + kg * 8);
      const ushort4 b4 = *reinterpret_cast<const ushort4*>(
          bias + (size_t)h * S * S + (size_t)(q0 + n16) * S + t0 + ts * 16 + kg * 4);
      f32x4 a;
      a[0] = b2f(b4.x); a[1] = b2f(b4.y); a[2] = b2f(b4.z); a[3] = b2f(b4.w);
      a = __builtin_amdgcn_mfma_f32_16x16x32_bf16(kh0, qh0, a, 0, 0, 0);
      a = __builtin_amdgcn_mfma_f32_16x16x32_bf16(kh1, qh1, a, 0, 0, 0);
      sc[ts] = a;
    }

    float tmax = sc[0][0];
#pragma unroll
    for (int ts = 0; ts < 4; ++ts)
#pragma unroll
      for (int r = 0; r < 4; ++r) tmax = fmaxf(tmax, sc[ts][r]);
    tmax = fmaxf(tmax, __shfl_xor(tmax, 16));
    tmax = fmaxf(tmax, __shfl_xor(tmax, 32));
    const float mn = fmaxf(mrow, tmax);
    const float fac = __expf(mrow - mn);
    mrow = mn;
    float psum = 0.f;
#pragma unroll
    for (int ts = 0; ts < 4; ++ts) {
      const float p0_ = __expf(sc[ts][0] - mn), p1_ = __expf(sc[ts][1] - mn);
      const float p2_ = __expf(sc[ts][2] - mn), p3_ = __expf(sc[ts][3] - mn);
      psum += (p0_ + p1_) + (p2_ + p3_);
      const int ti = ts * 16 + kg * 4;
      unsigned* wh = reinterpret_cast<unsigned*>(&php[n16 * PST + ti]);
      wh[0] = pack2(f2b(p0_), f2b(p1_));
      wh[1] = pack2(f2b(p2_), f2b(p3_));
    }
    lrow = lrow * fac + psum;

    float facr[4];
#pragma unroll
    for (int r = 0; r < 4; ++r) facr[r] = __shfl(fac, kg * 4 + r);
#pragma unroll
    for (int ds = 0; ds < 3; ++ds)
#pragma unroll
      for (int r = 0; r < 4; ++r) accO[ds][r] *= facr[r];

#pragma unroll
    for (int c = 0; c < 2; ++c) {
      const bf16x8 pah = *reinterpret_cast<const bf16x8*>(&php[n16 * PST + c * 32 + kg * 8]);
#pragma unroll
      for (int ds = 0; ds < 3; ++ds) {
        const size_t vb = (size_t)(h * 48 + ds * 16 + n16) * 1024 + t0 + c * 32 + kg * 8;
        const bf16x8 vh = *reinterpret_cast<const bf16x8*>(vt_hi + vb);
        accO[ds] = __builtin_amdgcn_mfma_f32_16x16x32_bf16(pah, vh, accO[ds], 0, 0, 0);
      }
    }
  }

  lrow += __shfl_xor(lrow, 16);
  lrow += __shfl_xor(lrow, 32);

  float* pw = Pr[wv];
#pragma unroll
  for (int ds = 0; ds < 3; ++ds)
#pragma unroll
    for (int r = 0; r < 4; ++r)
      pw[(kg * 4 + r) * PRS + ds * 16 + n16] = accO[ds][r];
  if (kg == 0) {
    pw[n16 * PRS + 48] = mrow;
    pw[n16 * PRS + 49] = lrow;
  }
  __syncthreads();

  const int row = threadIdx.x >> 4;
  const int dsub = threadIdx.x & 15;
  const float m0_ = Pr[0][row * PRS + 48], m1_ = Pr[1][row * PRS + 48];
  const float m2_ = Pr[2][row * PRS + 48], m3_ = Pr[3][row * PRS + 48];
  const float l0_ = Pr[0][row * PRS + 49], l1_ = Pr[1][row * PRS + 49];
  const float l2_ = Pr[2][row * PRS + 49], l3_ = Pr[3][row * PRS + 49];
  const float M = fmaxf(fmaxf(m0_, m1_), fmaxf(m2_, m3_));
  const float e0 = __expf(m0_ - M), e1 = __expf(m1_ - M);
  const float e2 = __expf(m2_ - M), e3 = __expf(m3_ - M);
  const float rl = 1.f / (l0_ * e0 + l1_ * e1 + l2_ * e2 + l3_ * e3);
#pragma unroll
  for (int j = 0; j < 3; ++j) {
    const int d = dsub * 3 + j;
    const float o = (Pr[0][row * PRS + d] * e0 + Pr[1][row * PRS + d] * e1 +
                     Pr[2][row * PRS + d] * e2 + Pr[3][row * PRS + d] * e3) * rl;
    const size_t idx = (size_t)(q0 + row) * D + h * 48 + d;
    const float a = o * sigmoidf_(g[idx]);
    a_hi[idx] = f2b(a);
  }
}

// ===========================================================================
// outproj: a_hi x (Wo_hi + Wo_lo), split-K x2.
// ===========================================================================
__global__ __launch_bounds__(256)
void outproj_mfma_kernel(const unsigned short* __restrict__ a_hi,
                         const unsigned short* __restrict__ wo_hi,
                         const unsigned short* __restrict__ wo_lo,
                         float* __restrict__ out) {
  __shared__ float CB[2][64][9];
  const int wv = threadIdx.x >> 6;
  const int pair = wv >> 1;
  const int khalf = wv & 1;
  const int tileid = blockIdx.x * 2 + pair;   // 0..1535
  const int m0 = (tileid / 48) * 32, n0 = (tileid % 48) * 16;
  const int lane = threadIdx.x & 63;
  const int r16 = lane & 15, kg = lane >> 4;
  const unsigned short* pah = a_hi + (size_t)(m0 + r16) * D + kg * 8;
  const unsigned short* pbh = wo_hi + (size_t)(n0 + r16) * D + kg * 8;
  const unsigned short* pbl = wo_lo + (size_t)(n0 + r16) * D + kg * 8;
  f32x4 a0 = {0.f, 0.f, 0.f, 0.f}, a1 = a0;
#pragma unroll 2
  for (int k = khalf * 384; k < khalf * 384 + 384; k += 32) {
    const bf16x8 ah0 = *reinterpret_cast<const bf16x8*>(pah + k);
    const bf16x8 ah1 = *reinterpret_cast<const bf16x8*>(pah + 16 * D + k);
    const bf16x8 bh0 = *reinterpret_cast<const bf16x8*>(pbh + k);
    const bf16x8 bl0 = *reinterpret_cast<const bf16x8*>(pbl + k);
    a0 = __builtin_amdgcn_mfma_f32_16x16x32_bf16(ah0, bh0, a0, 0, 0, 0);
    a0 = __builtin_amdgcn_mfma_f32_16x16x32_bf16(ah0, bl0, a0, 0, 0, 0);
    a1 = __builtin_amdgcn_mfma_f32_16x16x32_bf16(ah1, bh0, a1, 0, 0, 0);
    a1 = __builtin_amdgcn_mfma_f32_16x16x32_bf16(ah1, bl0, a1, 0, 0, 0);
  }
  if (khalf == 1) {
#pragma unroll
    for (int r = 0; r < 4; ++r) {
      CB[pair][lane][r] = a0[r];
      CB[pair][lane][4 + r] = a1[r];
    }
  }
  __syncthreads();
  if (khalf == 1) return;
#pragma unroll
  for (int r = 0; r < 4; ++r) {
    a0[r] += CB[pair][lane][r];
    a1[r] += CB[pair][lane][4 + r];
  }
#pragma unroll
  for (int r = 0; r < 4; ++r) {
    out[(size_t)(m0 + kg * 4 + r) * D + n0 + r16] = a0[r];
    out[(size_t)(m0 + 16 + kg * 4 + r) * D + n0 + r16] = a1[r];
  }
}

extern "C" void kernel_launch(void* const* d_in, const int* in_sizes, int n_in,
                              void* d_out, int out_size, void* d_ws, size_t ws_size,
                              hipStream_t stream) {
  const float* s    = (const float*)d_in[0];
  const float* z    = (const float*)d_in[1];
  const float* Wq   = (const float*)d_in[2];
  const float* bq   = (const float*)d_in[3];
  const float* Wk   = (const float*)d_in[4];
  const float* Wv   = (const float*)d_in[5];
  const float* Wg   = (const float*)d_in[6];
  const float* ln_w = (const float*)d_in[7];
  const float* ln_b = (const float*)d_in[8];
  const float* Wz   = (const float*)d_in[9];
  const float* Wo   = (const float*)d_in[10];
  float* out = (float*)d_out;

  float* g_ws    = (float*)d_ws;                                  // S*D f32
  float* s12_ws  = g_ws + (size_t)S * D;                          // 32 f32
  unsigned short* bias16 = (unsigned short*)(s12_ws + 32);        // H*S*S u16 (bf16)
  unsigned short* wzwb_ws = bias16 + (size_t)H * S * S;           // 2048 u16
  unsigned short* s_hi = wzwb_ws + 2048;                          // S*D
  unsigned short* w_hi = s_hi + (size_t)S * D;                    // 5*D*D
  unsigned short* wo_lo = w_hi + (size_t)5 * D * D;               // D*D (Wo lo)
  unsigned short* a_hi = wo_lo + (size_t)D * D;                   // S*D
  unsigned short* q_hi = a_hi + (size_t)S * D;                    // [S][1024] padded
  unsigned short* k_hi = q_hi + (size_t)S * 1024;
  unsigned short* vt_hi = k_hi + (size_t)S * 1024;                // [768][1024]

  // A) splits (hi-only except Wo) + pb_prep + padzero
  prep_kernel<<<dim3(812, 6), 256, 0, stream>>>(s, Wq, Wk, Wv, Wg, Wo,
                                                s_hi, w_hi, wo_lo,
                                                Wz, ln_w, ln_b, wzwb_ws, s12_ws,
                                                q_hi, k_hi);
  // B) qkvg (plain bf16, split-K x2) + pair_bias (bf16 bias out)
  qkvg_mfma_kernel<<<1536, 256, 0, stream>>>(s_hi, w_hi, bq,
                                             q_hi, k_hi, vt_hi, g_ws);
  pair_bias_kernel<<<4096, 256, 0, stream>>>(z, wzwb_ws, s12_ws, bias16);
  // C) fused 4-way KV-split attention (QK hi; bias bf16; PV hi; gate fused)
  attn_kernel<<<1024, 256, 0, stream>>>(q_hi, k_hi, vt_hi,
                                        bias16, g_ws, a_hi);
  // D) output projection (a hi x Wo split)
  outproj_mfma_kernel<<<768, 256, 0, stream>>>(a_hi, w_hi + (size_t)4 * D * D,
                                               wo_lo, out);
}